// Round 7
// baseline (222.437 us; speedup 1.0000x reference)
//
#include <hip/hip_runtime.h>
#include <hip/hip_bf16.h>

// Causal self-attention fwd, B=2 S=2048 H=16 D=64, f32 in/out, bf16 MFMA inside.
// Round 7: software-pipelined kv loop — ONE barrier/iter; softmax(i) overlaps
// the in-flight stage(i+1); QK(i+1) + V(i)->regs in one LDS cluster after the
// barrier; PV(i) MFMAs overlap next iteration's softmax VALU. 2x-unrolled loop
// with sacc role swap. Same math as round 6 (swapped QK^T, in-register softmax,
// bpermute P^T assembly, defer-rescale, pre-scaled Q, pre-swizzled K/V^T tiles).

#define Bsz 2
#define Ssz 2048
#define Hsz 16
#define Dsz 64
#define BH (Bsz * Hsz)

typedef short bf16x8 __attribute__((ext_vector_type(8)));
typedef float f32x4  __attribute__((ext_vector_type(4)));

constexpr float SCL2 = 0.125f * 1.44269504088896340736f;  // scale * log2(e)
constexpr float NEGI = -1e30f;
constexpr float THR  = 10.0f;   // defer-rescale threshold (exp2 domain)
constexpr size_t NEL = (size_t)BH * Ssz * Dsz;  // 4,194,304 shorts per array

__device__ __forceinline__ short f2b(float f) {
  __hip_bfloat16 h = __float2bfloat16(f);
  return *reinterpret_cast<short*>(&h);
}

__device__ __forceinline__ unsigned pk2(float a, float b) {
  __hip_bfloat162 h2 = __float22bfloat162_rn(make_float2(a, b));
  unsigned u; __builtin_memcpy(&u, &h2, 4); return u;
}

typedef const __attribute__((address_space(1))) unsigned int* gas_p;
typedef __attribute__((address_space(3))) unsigned int* las_p;

__device__ __forceinline__ void lds16(const short* g, short* l) {
  gas_p gp = (gas_p)(uintptr_t)g;
  las_p lp = (las_p)(uintptr_t)l;
  __builtin_amdgcn_global_load_lds(gp, lp, 16, 0, 0);
}

// ---------------- pre-pass: Q (pre-scaled) and K (pre-swizzled tiles) ----------------
__global__ __launch_bounds__(256)
void prep_qk(const float* __restrict__ qkv, short* __restrict__ dst0) {
  const int which = blockIdx.y;  // 0 = Q, 1 = K
  const int T = blockIdx.x * 256 + threadIdx.x;
  const int p  = T & 7;
  const int s  = (T >> 3) & (Ssz - 1);
  const int bh = T >> 14;
  const int b = bh >> 4, h = bh & 15;
  const int c = which ? (p ^ (s & 7)) : p;   // source 8-elem chunk within row
  const float sc = which ? 1.0f : SCL2;      // fold softmax scale into Q
  const float* src = qkv + (((size_t)(b * Ssz + s) * 3 + which) * Hsz + h) * Dsz + 8 * c;
  float4 f0 = reinterpret_cast<const float4*>(src)[0];
  float4 f1 = reinterpret_cast<const float4*>(src)[1];
  bf16x8 v;
  v[0] = f2b(f0.x * sc); v[1] = f2b(f0.y * sc); v[2] = f2b(f0.z * sc); v[3] = f2b(f0.w * sc);
  v[4] = f2b(f1.x * sc); v[5] = f2b(f1.y * sc); v[6] = f2b(f1.z * sc); v[7] = f2b(f1.w * sc);
  *reinterpret_cast<bf16x8*>(dst0 + (size_t)which * NEL + (size_t)T * 8) = v;
}

// ---------------- pre-pass: V -> V^T pre-swizzled tiles ----------------
__global__ __launch_bounds__(256)
void prep_vt(const float* __restrict__ qkv, short* __restrict__ vt) {
  __shared__ short Ls[64][72];
  const int tile = blockIdx.x;
  const int s0 = tile * 64;
  const int bh = blockIdx.y;
  const int b = bh >> 4, h = bh & 15;
  const int t = threadIdx.x;
  {
    const int srow = t >> 2;
    const int dc = (t & 3) * 16;
    const float* src = qkv + (((size_t)(b * Ssz + s0 + srow) * 3 + 2) * Hsz + h) * Dsz + dc;
    float4 a0 = reinterpret_cast<const float4*>(src)[0];
    float4 a1 = reinterpret_cast<const float4*>(src)[1];
    float4 a2 = reinterpret_cast<const float4*>(src)[2];
    float4 a3 = reinterpret_cast<const float4*>(src)[3];
    bf16x8 lo, hi;
    lo[0] = f2b(a0.x); lo[1] = f2b(a0.y); lo[2] = f2b(a0.z); lo[3] = f2b(a0.w);
    lo[4] = f2b(a1.x); lo[5] = f2b(a1.y); lo[6] = f2b(a1.z); lo[7] = f2b(a1.w);
    hi[0] = f2b(a2.x); hi[1] = f2b(a2.y); hi[2] = f2b(a2.z); hi[3] = f2b(a2.w);
    hi[4] = f2b(a3.x); hi[5] = f2b(a3.y); hi[6] = f2b(a3.z); hi[7] = f2b(a3.w);
    *reinterpret_cast<bf16x8*>(&Ls[srow][dc])     = lo;
    *reinterpret_cast<bf16x8*>(&Ls[srow][dc + 8]) = hi;
  }
  __syncthreads();
  {
    const int d = t >> 2;
    short* drow = vt + (size_t)bh * (32 * 4096) + (size_t)tile * 4096 + d * 64;
#pragma unroll
    for (int pp = 0; pp < 2; ++pp) {
      const int p = (t & 3) * 2 + pp;
      const int sbase = 8 * (p ^ (d & 7));
      bf16x8 w;
#pragma unroll
      for (int e = 0; e < 8; ++e) w[e] = Ls[sbase + e][d];
      *reinterpret_cast<bf16x8*>(drow + p * 8) = w;
    }
  }
}

// ---------------- main: pipelined flash attention ----------------
__global__ __launch_bounds__(256, 4)
void attn_main(const short* __restrict__ Qb, const short* __restrict__ Kt,
               const short* __restrict__ Vt, float* __restrict__ out) {
  const int qi = (Ssz / 64) - 1 - (int)blockIdx.x;  // heavy (long-loop) tiles first
  const int bh = blockIdx.y;
  const int b = bh >> 4, h = bh & 15;
  const int tid = threadIdx.x;
  const int w = tid >> 6, lane = tid & 63, l15 = lane & 15, lq = lane >> 4;
  const int q0 = qi * 64;

  __shared__ short Kbuf[2][4096];   // 2 x 8KB, swizzled [64 s][8 chunk]
  __shared__ short Vbuf[2][4096];   // 2 x 8KB, swizzled [64 d][8 chunk]

  // Q fragment (B operand of swapped QK^T): col = l15 (q row), k(d) = 32c + 8lq + e
  const int tq = q0 + 16 * w + l15;
  const short* qrow = Qb + ((size_t)bh * Ssz + tq) * Dsz;
  const bf16x8 bq0 = *reinterpret_cast<const bf16x8*>(qrow + 8 * lq);
  const bf16x8 bq1 = *reinterpret_cast<const bf16x8*>(qrow + 32 + 8 * lq);

  const short* Ksrc = Kt + (size_t)bh * (32 * 4096);
  const short* Vsrc = Vt + (size_t)bh * (32 * 4096);

  const int selA = ((lq)     ^ (l15 & 7)) << 4;
  const int selB = ((4 + lq) ^ (l15 & 7)) << 4;
  const char* kbase = (const char*)Kbuf;
  const char* vbase = (const char*)Vbuf;

  // bpermute source lanes for P^T exchange
  const int srcA = ((2 * lq) & 3) * 16 + l15;
  const int srcB = ((2 * lq + 1) & 3) * 16 + l15;
  const bool hiq = (lq >= 2);

  float m = NEGI, lsum = 0.f;
  f32x4 oacc[4];
#pragma unroll
  for (int dt = 0; dt < 4; ++dt)
#pragma unroll
    for (int r = 0; r < 4; ++r) oacc[dt][r] = 0.f;

  const int t_wave_hi = q0 + 16 * w + 15;

  auto stage = [&](int kvb) {
    const int buf = kvb & 1;
    const short* ks = Ksrc + (size_t)kvb * 4096;
    const short* vs = Vsrc + (size_t)kvb * 4096;
    short* kl = (short*)((char*)Kbuf + buf * 8192 + w * 1024);
    short* vl = (short*)((char*)Vbuf + buf * 8192 + w * 1024);
    lds16(ks + (w * 64 + lane) * 8, kl);
    lds16(ks + (256 + w * 64 + lane) * 8, (short*)((char*)kl + 4096));
    lds16(vs + (w * 64 + lane) * 8, vl);
    lds16(vs + (256 + w * 64 + lane) * 8, (short*)((char*)vl + 4096));
  };

  // swapped QK^T for tile n: sa[j] holds S^T[s=64n+16j+4lq+r][t=l15]
  auto qk = [&](int n, f32x4 (&sa)[4]) {
    const bool dg = (n == qi);
    const char* kb = kbase + (n & 1) * 8192;
#pragma unroll
    for (int j = 0; j < 4; ++j) {
#pragma unroll
      for (int r = 0; r < 4; ++r) sa[j][r] = 0.f;
      if (!dg || n * 64 + 16 * j <= t_wave_hi) {   // wave-uniform skip
        const char* krow = kb + (16 * j + l15) * 128;
        bf16x8 bk0 = *reinterpret_cast<const bf16x8*>(krow + selA);
        bf16x8 bk1 = *reinterpret_cast<const bf16x8*>(krow + selB);
        sa[j] = __builtin_amdgcn_mfma_f32_16x16x32_bf16(bk0, bq0, sa[j], 0, 0, 0);
        sa[j] = __builtin_amdgcn_mfma_f32_16x16x32_bf16(bk1, bq1, sa[j], 0, 0, 0);
      }
    }
  };

  // iteration i: softmax+PV on sA (tile i); QK(i+1) -> sB
  auto iter = [&](int i, f32x4 (&sA)[4], f32x4 (&sB)[4]) {
    const bool dg = (i == qi);
    const int s0 = i * 64;

    // ---- causal mask (diag only) ----
    float vals[4][4];
    if (dg) {
#pragma unroll
      for (int j = 0; j < 4; ++j)
#pragma unroll
        for (int r = 0; r < 4; ++r) {
          const int srow = s0 + 16 * j + 4 * lq + r;
          vals[j][r] = (srow <= tq) ? sA[j][r] : NEGI;
        }
    } else {
#pragma unroll
      for (int j = 0; j < 4; ++j)
#pragma unroll
        for (int r = 0; r < 4; ++r) vals[j][r] = sA[j][r];
    }

    // ---- row max: in-lane tree + 2 shfl ----
    float m4[4];
#pragma unroll
    for (int j = 0; j < 4; ++j)
      m4[j] = fmaxf(fmaxf(vals[j][0], vals[j][1]), fmaxf(vals[j][2], vals[j][3]));
    float bm = fmaxf(fmaxf(m4[0], m4[1]), fmaxf(m4[2], m4[3]));
    bm = fmaxf(bm, __shfl_xor(bm, 16));
    bm = fmaxf(bm, __shfl_xor(bm, 32));

    // ---- defer-rescale (wave-uniform) ----
    if (__any(bm > m + THR)) {
      const float newm = fmaxf(m, bm);
      const float es = exp2f(m - newm);
      lsum *= es;
#pragma unroll
      for (int dt = 0; dt < 4; ++dt)
#pragma unroll
        for (int r = 0; r < 4; ++r) oacc[dt][r] *= es;
      m = newm;
    }

    // ---- P = exp2(S^T - m), row sum, pack ----
    float p[4][4];
#pragma unroll
    for (int j = 0; j < 4; ++j)
#pragma unroll
      for (int r = 0; r < 4; ++r) p[j][r] = exp2f(vals[j][r] - m);
    float s4[4];
#pragma unroll
    for (int j = 0; j < 4; ++j)
      s4[j] = (p[j][0] + p[j][1]) + (p[j][2] + p[j][3]);
    float ps = (s4[0] + s4[1]) + (s4[2] + s4[3]);
    ps += __shfl_xor(ps, 16);
    ps += __shfl_xor(ps, 32);
    lsum += ps;

    unsigned Dw[4][2];
#pragma unroll
    for (int j = 0; j < 4; ++j) {
      Dw[j][0] = pk2(p[j][0], p[j][1]);
      Dw[j][1] = pk2(p[j][2], p[j][3]);
    }

    // ---- assemble P^T B-fragments in-register ----
    bf16x8 pt[2];
#pragma unroll
    for (int c = 0; c < 2; ++c) {
      const int jl = 2 * c, jh = 2 * c + 1;
      unsigned a0 = __shfl(Dw[jl][0], srcA), a1 = __shfl(Dw[jl][1], srcA);
      unsigned a2 = __shfl(Dw[jl][0], srcB), a3 = __shfl(Dw[jl][1], srcB);
      unsigned b0 = __shfl(Dw[jh][0], srcA), b1 = __shfl(Dw[jh][1], srcA);
      unsigned b2 = __shfl(Dw[jh][0], srcB), b3 = __shfl(Dw[jh][1], srcB);
      union { unsigned u[4]; bf16x8 v; } uu;
      uu.u[0] = hiq ? b0 : a0;
      uu.u[1] = hiq ? b1 : a1;
      uu.u[2] = hiq ? b2 : a2;
      uu.u[3] = hiq ? b3 : a3;
      pt[c] = uu.v;
    }

    // ---- barrier for tile i+1, then one LDS read cluster ----
    if (i < qi) {
      asm volatile("s_waitcnt vmcnt(0)" ::: "memory");  // stage(i+1) landed
      __builtin_amdgcn_s_barrier();
      __builtin_amdgcn_sched_barrier(0);
    }

    // V(i) -> regs (tile i resident since last barrier; next write to this
    // buffer is stage(i+2), issued below after lgkmcnt(0))
    bf16x8 vv[4][2];
    const char* vb = vbase + (i & 1) * 8192;
#pragma unroll
    for (int dt = 0; dt < 4; ++dt) {
      const char* vrow = vb + (16 * dt + l15) * 128;
      vv[dt][0] = *reinterpret_cast<const bf16x8*>(vrow + selA);
      vv[dt][1] = *reinterpret_cast<const bf16x8*>(vrow + selB);
    }

    if (i < qi) {
      qk(i + 1, sB);                       // K ds_reads + MFMA (tile i+1)
      if (i + 2 <= qi) {
        asm volatile("s_waitcnt lgkmcnt(0)" ::: "memory");  // all ds_reads done
        __builtin_amdgcn_sched_barrier(0);
        stage(i + 2);                      // overwrite tile-i buffer
      }
    }

    // ---- PV: runs in MFMA pipe while next softmax VALU issues ----
#pragma unroll
    for (int dt = 0; dt < 4; ++dt) {
      oacc[dt] = __builtin_amdgcn_mfma_f32_16x16x32_bf16(vv[dt][0], pt[0], oacc[dt], 0, 0, 0);
      oacc[dt] = __builtin_amdgcn_mfma_f32_16x16x32_bf16(vv[dt][1], pt[1], oacc[dt], 0, 0, 0);
    }
  };

  // ---- prologue ----
  stage(0);
  asm volatile("s_waitcnt vmcnt(0)" ::: "memory");
  __builtin_amdgcn_s_barrier();
  __builtin_amdgcn_sched_barrier(0);
  f32x4 sA[4], sB[4];
  qk(0, sA);
  if (qi >= 1) stage(1);

  // ---- 2x-unrolled pipelined loop (role swap, all static indexing) ----
  int i = 0;
  while (true) {
    iter(i, sA, sB);
    if (++i > qi) break;
    iter(i, sB, sA);
    if (++i > qi) break;
  }

  // ---- epilogue: normalize, float4 stores (lane owns row tq, d = 16dt+4lq+r) ----
  const float inv = 1.f / lsum;
  float* orow = out + (((size_t)(b * Ssz + tq) * Hsz) + h) * Dsz;
#pragma unroll
  for (int dt = 0; dt < 4; ++dt) {
    float4 st;
    st.x = oacc[dt][0] * inv;
    st.y = oacc[dt][1] * inv;
    st.z = oacc[dt][2] * inv;
    st.w = oacc[dt][3] * inv;
    *reinterpret_cast<float4*>(orow + 16 * dt + 4 * lq) = st;
  }
}

// ---------------- fallback (round-2 kernel) if ws too small ----------------
constexpr int QT = 64;
constexpr int KT = 64;
constexpr int LDKfb = 72;

__global__ __launch_bounds__(256)
void attn_fwd_fb(const float* __restrict__ qkv, float* __restrict__ out) {
  const int qi   = (Ssz / QT) - 1 - (int)blockIdx.x;
  const int bh   = blockIdx.y;
  const int b    = bh >> 4;
  const int h    = bh & 15;
  const int tid  = threadIdx.x;
  const int wave = tid >> 6;
  const int lane = tid & 63;
  const int l15  = lane & 15;
  const int lq   = lane >> 4;
  const int q0   = qi * QT;

  __shared__ short Kl[KT][LDKfb];
  __shared__ short Vtl[Dsz][LDKfb];
  __shared__ short Pl[4][16][LDKfb];

  bf16x8 aq[2];
  {
    const int tqf = q0 + wave * 16 + l15;
    const float* qrowf = qkv + (((size_t)(b * Ssz + tqf) * 3 + 0) * Hsz + h) * Dsz;
#pragma unroll
    for (int c = 0; c < 2; ++c) {
      const float* p = qrowf + 32 * c + 8 * lq;
      float4 f0 = reinterpret_cast<const float4*>(p)[0];
      float4 f1 = reinterpret_cast<const float4*>(p)[1];
      bf16x8 v;
      v[0] = f2b(f0.x); v[1] = f2b(f0.y); v[2] = f2b(f0.z); v[3] = f2b(f0.w);
      v[4] = f2b(f1.x); v[5] = f2b(f1.y); v[6] = f2b(f1.z); v[7] = f2b(f1.w);
      aq[c] = v;
    }
  }

  float mrow[4], lsum[4];
  f32x4 oacc[4];
#pragma unroll
  for (int r = 0; r < 4; ++r) { mrow[r] = NEGI; lsum[r] = 0.f; }
#pragma unroll
  for (int dt = 0; dt < 4; ++dt)
#pragma unroll
    for (int r = 0; r < 4; ++r) oacc[dt][r] = 0.f;

  const int t_wave_hi = q0 + wave * 16 + 15;
  const int trow      = q0 + wave * 16 + 4 * lq;
  const int nkv       = qi + 1;

  const int pr   = tid >> 3;
  const int srow = 2 * pr;
  const int d0   = (tid & 7) * 8;
  const int Fw   = tid & 7;
  const int swc  = srow ^ (Fw << 3);

  for (int kvb = 0; kvb < nkv; ++kvb) {
    const int s0 = kvb * KT;
    {
      const float* kr0 = qkv + (((size_t)(b * Ssz + s0 + srow) * 3 + 1) * Hsz + h) * Dsz + d0;
      const float* kr1 = kr0 + 3 * Hsz * Dsz;
      const float* vr0 = kr0 + Hsz * Dsz;
      const float* vr1 = vr0 + 3 * Hsz * Dsz;
      float4 ka0 = reinterpret_cast<const float4*>(kr0)[0];
      float4 ka1 = reinterpret_cast<const float4*>(kr0)[1];
      float4 kb0 = reinterpret_cast<const float4*>(kr1)[0];
      float4 kb1 = reinterpret_cast<const float4*>(kr1)[1];
      float4 va0 = reinterpret_cast<const float4*>(vr0)[0];
      float4 va1 = reinterpret_cast<const float4*>(vr0)[1];
      float4 vb0 = reinterpret_cast<const float4*>(vr1)[0];
      float4 vb1 = reinterpret_cast<const float4*>(vr1)[1];

      bf16x8 kw0, kw1;
      kw0[0] = f2b(ka0.x); kw0[1] = f2b(ka0.y); kw0[2] = f2b(ka0.z); kw0[3] = f2b(ka0.w);
      kw0[4] = f2b(ka1.x); kw0[5] = f2b(ka1.y); kw0[6] = f2b(ka1.z); kw0[7] = f2b(ka1.w);
      kw1[0] = f2b(kb0.x); kw1[1] = f2b(kb0.y); kw1[2] = f2b(kb0.z); kw1[3] = f2b(kb0.w);
      kw1[4] = f2b(kb1.x); kw1[5] = f2b(kb1.y); kw1[6] = f2b(kb1.z); kw1[7] = f2b(kb1.w);
      *reinterpret_cast<bf16x8*>(&Kl[srow][d0])     = kw0;
      *reinterpret_cast<bf16x8*>(&Kl[srow + 1][d0]) = kw1;

      float va[8] = {va0.x, va0.y, va0.z, va0.w, va1.x, va1.y, va1.z, va1.w};
      float vb[8] = {vb0.x, vb0.y, vb0.z, vb0.w, vb1.x, vb1.y, vb1.z, vb1.w};
#pragma unroll
      for (int j = 0; j < 8; ++j) {
        __hip_bfloat162 h2 = __float22bfloat162_rn(make_float2(va[j], vb[j]));
        *reinterpret_cast<unsigned*>(&Vtl[d0 + j][swc]) =
            *reinterpret_cast<unsigned*>(&h2);
      }
    }
    __syncthreads();

    f32x4 sacc[4];
#pragma unroll
    for (int j = 0; j < 4; ++j)
#pragma unroll
      for (int r = 0; r < 4; ++r) sacc[j][r] = 0.f;
#pragma unroll
    for (int j = 0; j < 4; ++j) {
      if (s0 + 16 * j <= t_wave_hi) {
#pragma unroll
        for (int c = 0; c < 2; ++c) {
          bf16x8 bk = *reinterpret_cast<const bf16x8*>(&Kl[16 * j + l15][32 * c + 8 * lq]);
          sacc[j] = __builtin_amdgcn_mfma_f32_16x16x32_bf16(aq[c], bk, sacc[j], 0, 0, 0);
        }
      }
    }

    const bool diag = (kvb == nkv - 1);
    float vals[4][4], bm[4];
#pragma unroll
    for (int r = 0; r < 4; ++r) bm[r] = NEGI;
    if (diag) {
#pragma unroll
      for (int j = 0; j < 4; ++j) {
        const bool actj = (s0 + 16 * j <= t_wave_hi);
        const int scol = s0 + 16 * j + l15;
#pragma unroll
        for (int r = 0; r < 4; ++r) {
          float v = (actj && scol <= trow + r) ? sacc[j][r] * SCL2 : NEGI;
          vals[j][r] = v;
          bm[r] = fmaxf(bm[r], v);
        }
      }
    } else {
#pragma unroll
      for (int j = 0; j < 4; ++j)
#pragma unroll
        for (int r = 0; r < 4; ++r) {
          float v = sacc[j][r] * SCL2;
          vals[j][r] = v;
          bm[r] = fmaxf(bm[r], v);
        }
    }
#pragma unroll
    for (int off = 1; off < 16; off <<= 1)
#pragma unroll
      for (int r = 0; r < 4; ++r)
        bm[r] = fmaxf(bm[r], __shfl_xor(bm[r], off));

    float es[4], ps[4];
#pragma unroll
    for (int r = 0; r < 4; ++r) {
      const float mn = fmaxf(mrow[r], bm[r]);
      es[r] = exp2f(mrow[r] - mn);
      mrow[r] = mn;
      ps[r] = 0.f;
    }
#pragma unroll
    for (int j = 0; j < 4; ++j)
#pragma unroll
      for (int r = 0; r < 4; ++r) {
        float p = exp2f(vals[j][r] - mrow[r]);
        ps[r] += p;
        Pl[wave][4 * lq + r][16 * j + l15] = f2b(p);
      }
#pragma unroll
    for (int off = 1; off < 16; off <<= 1)
#pragma unroll
      for (int r = 0; r < 4; ++r)
        ps[r] += __shfl_xor(ps[r], off);
#pragma unroll
    for (int r = 0; r < 4; ++r)
      lsum[r] = lsum[r] * es[r] + ps[r];
#pragma unroll
    for (int dt = 0; dt < 4; ++dt)
#pragma unroll
      for (int r = 0; r < 4; ++r)
        oacc[dt][r] *= es[r];

    asm volatile("" ::: "memory");

    {
      bf16x8 ap0 = *reinterpret_cast<const bf16x8*>(&Pl[wave][l15][8 * lq]);
      bf16x8 ap1 = *reinterpret_cast<const bf16x8*>(&Pl[wave][l15][32 + 8 * lq]);
#pragma unroll
      for (int dt = 0; dt < 4; ++dt) {
        const int d = 16 * dt + l15;
        const int F = (d >> 3) & 7;
        bf16x8 bv0 = *reinterpret_cast<const bf16x8*>(&Vtl[d][((lq ^ F) << 3)]);
        bf16x8 bv1 = *reinterpret_cast<const bf16x8*>(&Vtl[d][(((4 + lq) ^ F) << 3)]);
        oacc[dt] = __builtin_amdgcn_mfma_f32_16x16x32_bf16(ap0, bv0, oacc[dt], 0, 0, 0);
        oacc[dt] = __builtin_amdgcn_mfma_f32_16x16x32_bf16(ap1, bv1, oacc[dt], 0, 0, 0);
      }
    }
    __syncthreads();
  }

#pragma unroll
  for (int r = 0; r < 4; ++r) {
    const float inv = 1.f / lsum[r];
    const int t = trow + r;
    float* orow = out + (((size_t)(b * Ssz + t) * Hsz) + h) * Dsz;
#pragma unroll
    for (int dt = 0; dt < 4; ++dt)
      orow[16 * dt + l15] = oacc[dt][r] * inv;
  }
}

extern "C" void kernel_launch(void* const* d_in, const int* in_sizes, int n_in,
                              void* d_out, int out_size, void* d_ws, size_t ws_size,
                              hipStream_t stream) {
  const float* qkv = (const float*)d_in[0];
  float* out = (float*)d_out;
  const size_t need = 3 * NEL * sizeof(short);  // 25,165,824 B
  if (ws_size >= need) {
    short* Qb = (short*)d_ws;
    short* Kt = Qb + NEL;
    short* Vt = Qb + 2 * NEL;
    hipLaunchKernelGGL(prep_qk, dim3((unsigned)(NEL / 8 / 256), 2), dim3(256), 0, stream, qkv, Qb);
    hipLaunchKernelGGL(prep_vt, dim3(Ssz / 64, BH), dim3(256), 0, stream, qkv, Vt);
    hipLaunchKernelGGL(attn_main, dim3(Ssz / 64, BH), dim3(256), 0, stream, Qb, Kt, Vt, out);
  } else {
    hipLaunchKernelGGL(attn_fwd_fb, dim3(Ssz / QT, BH), dim3(256), 0, stream, qkv, out);
  }
}

// Round 8
// 90.009 us; speedup vs baseline: 2.4713x; 2.4713x over previous
//
#include <hip/hip_runtime.h>
#include <hip/hip_bf16.h>

// Causal self-attention fwd, B=2 S=2048 H=16 D=64, f32 in/out, bf16 MFMA inside.
// Round 8: round-6 kernel body (swapped QK^T, in-register softmax, bpermute P^T
// assembly, defer-rescale, pre-scaled Q, pre-swizzled K/V^T tiles, 2-barrier
// double-buffered global_load_lds staging) + PERFECT WORK BALANCE: each block
// processes q-tiles (x, 31-x) sequentially -> every block = 33 kv-iterations,
// no straggler tail. Grid (16, 32) = 512 blocks.

#define Bsz 2
#define Ssz 2048
#define Hsz 16
#define Dsz 64
#define BH (Bsz * Hsz)

typedef short bf16x8 __attribute__((ext_vector_type(8)));
typedef float f32x4  __attribute__((ext_vector_type(4)));

constexpr float SCL2 = 0.125f * 1.44269504088896340736f;  // scale * log2(e)
constexpr float NEGI = -1e30f;
constexpr float THR  = 10.0f;   // defer-rescale threshold (exp2 domain)
constexpr size_t NEL = (size_t)BH * Ssz * Dsz;  // 4,194,304 shorts per array

__device__ __forceinline__ short f2b(float f) {
  __hip_bfloat16 h = __float2bfloat16(f);
  return *reinterpret_cast<short*>(&h);
}

__device__ __forceinline__ unsigned pk2(float a, float b) {
  __hip_bfloat162 h2 = __float22bfloat162_rn(make_float2(a, b));
  unsigned u; __builtin_memcpy(&u, &h2, 4); return u;
}

typedef const __attribute__((address_space(1))) unsigned int* gas_p;
typedef __attribute__((address_space(3))) unsigned int* las_p;

__device__ __forceinline__ void lds16(const short* g, short* l) {
  gas_p gp = (gas_p)(uintptr_t)g;
  las_p lp = (las_p)(uintptr_t)l;
  __builtin_amdgcn_global_load_lds(gp, lp, 16, 0, 0);
}

// ---------------- pre-pass: Q (pre-scaled) and K (pre-swizzled tiles) ----------------
__global__ __launch_bounds__(256)
void prep_qk(const float* __restrict__ qkv, short* __restrict__ dst0) {
  const int which = blockIdx.y;  // 0 = Q, 1 = K
  const int T = blockIdx.x * 256 + threadIdx.x;
  const int p  = T & 7;
  const int s  = (T >> 3) & (Ssz - 1);
  const int bh = T >> 14;
  const int b = bh >> 4, h = bh & 15;
  const int c = which ? (p ^ (s & 7)) : p;   // source 8-elem chunk within row
  const float sc = which ? 1.0f : SCL2;      // fold softmax scale into Q
  const float* src = qkv + (((size_t)(b * Ssz + s) * 3 + which) * Hsz + h) * Dsz + 8 * c;
  float4 f0 = reinterpret_cast<const float4*>(src)[0];
  float4 f1 = reinterpret_cast<const float4*>(src)[1];
  bf16x8 v;
  v[0] = f2b(f0.x * sc); v[1] = f2b(f0.y * sc); v[2] = f2b(f0.z * sc); v[3] = f2b(f0.w * sc);
  v[4] = f2b(f1.x * sc); v[5] = f2b(f1.y * sc); v[6] = f2b(f1.z * sc); v[7] = f2b(f1.w * sc);
  *reinterpret_cast<bf16x8*>(dst0 + (size_t)which * NEL + (size_t)T * 8) = v;
}

// ---------------- pre-pass: V -> V^T pre-swizzled tiles ----------------
__global__ __launch_bounds__(256)
void prep_vt(const float* __restrict__ qkv, short* __restrict__ vt) {
  __shared__ short Ls[64][72];
  const int tile = blockIdx.x;
  const int s0 = tile * 64;
  const int bh = blockIdx.y;
  const int b = bh >> 4, h = bh & 15;
  const int t = threadIdx.x;
  {
    const int srow = t >> 2;
    const int dc = (t & 3) * 16;
    const float* src = qkv + (((size_t)(b * Ssz + s0 + srow) * 3 + 2) * Hsz + h) * Dsz + dc;
    float4 a0 = reinterpret_cast<const float4*>(src)[0];
    float4 a1 = reinterpret_cast<const float4*>(src)[1];
    float4 a2 = reinterpret_cast<const float4*>(src)[2];
    float4 a3 = reinterpret_cast<const float4*>(src)[3];
    bf16x8 lo, hi;
    lo[0] = f2b(a0.x); lo[1] = f2b(a0.y); lo[2] = f2b(a0.z); lo[3] = f2b(a0.w);
    lo[4] = f2b(a1.x); lo[5] = f2b(a1.y); lo[6] = f2b(a1.z); lo[7] = f2b(a1.w);
    hi[0] = f2b(a2.x); hi[1] = f2b(a2.y); hi[2] = f2b(a2.z); hi[3] = f2b(a2.w);
    hi[4] = f2b(a3.x); hi[5] = f2b(a3.y); hi[6] = f2b(a3.z); hi[7] = f2b(a3.w);
    *reinterpret_cast<bf16x8*>(&Ls[srow][dc])     = lo;
    *reinterpret_cast<bf16x8*>(&Ls[srow][dc + 8]) = hi;
  }
  __syncthreads();
  {
    const int d = t >> 2;
    short* drow = vt + (size_t)bh * (32 * 4096) + (size_t)tile * 4096 + d * 64;
#pragma unroll
    for (int pp = 0; pp < 2; ++pp) {
      const int p = (t & 3) * 2 + pp;
      const int sbase = 8 * (p ^ (d & 7));
      bf16x8 w;
#pragma unroll
      for (int e = 0; e < 8; ++e) w[e] = Ls[sbase + e][d];
      *reinterpret_cast<bf16x8*>(drow + p * 8) = w;
    }
  }
}

// ---------------- main: flash attention, paired q-tiles for balance ----------------
__global__ __launch_bounds__(256)
void attn_main(const short* __restrict__ Qb, const short* __restrict__ Kt,
               const short* __restrict__ Vt, float* __restrict__ out) {
  const int pair = blockIdx.x;           // 0..15 -> tiles (pair, 31-pair)
  const int bh = blockIdx.y;
  const int b = bh >> 4, h = bh & 15;
  const int tid = threadIdx.x;
  const int w = tid >> 6, lane = tid & 63, l15 = lane & 15, lq = lane >> 4;

  __shared__ short Kbuf[2][4096];   // 2 x 8KB, swizzled [64 s][8 chunk]
  __shared__ short Vbuf[2][4096];   // 2 x 8KB, swizzled [64 d][8 chunk]

  const short* Ksrc = Kt + (size_t)bh * (32 * 4096);
  const short* Vsrc = Vt + (size_t)bh * (32 * 4096);

  // tile-invariant swizzled ds_read offsets: row*128 + ((chunk ^ (l15&7))<<4)
  const int selA = ((lq)     ^ (l15 & 7)) << 4;
  const int selB = ((4 + lq) ^ (l15 & 7)) << 4;
  const char* kbase = (const char*)Kbuf;
  const char* vbase = (const char*)Vbuf;

  // bpermute source lanes for P^T exchange
  const int srcA = ((2 * lq) & 3) * 16 + l15;
  const int srcB = ((2 * lq + 1) & 3) * 16 + l15;
  const bool hiq = (lq >= 2);

  auto stage = [&](int buf, int kvb) {
    const short* ks = Ksrc + (size_t)kvb * 4096;
    const short* vs = Vsrc + (size_t)kvb * 4096;
    short* kl = (short*)((char*)Kbuf + buf * 8192 + w * 1024);
    short* vl = (short*)((char*)Vbuf + buf * 8192 + w * 1024);
    lds16(ks + (w * 64 + lane) * 8, kl);
    lds16(ks + (256 + w * 64 + lane) * 8, (short*)((char*)kl + 4096));
    lds16(vs + (w * 64 + lane) * 8, vl);
    lds16(vs + (256 + w * 64 + lane) * 8, (short*)((char*)vl + 4096));
  };

#pragma unroll 1
  for (int half = 0; half < 2; ++half) {
    const int qi = half ? (31 - pair) : pair;
    const int q0 = qi * 64;

    // Q fragment (B operand of swapped QK^T): col = l15 (q row), k(d) = 32c + 8lq + e
    const int tq = q0 + 16 * w + l15;
    const short* qrow = Qb + ((size_t)bh * Ssz + tq) * Dsz;
    const bf16x8 bq0 = *reinterpret_cast<const bf16x8*>(qrow + 8 * lq);
    const bf16x8 bq1 = *reinterpret_cast<const bf16x8*>(qrow + 32 + 8 * lq);

    float m = NEGI, lsum = 0.f;
    f32x4 oacc[4];
#pragma unroll
    for (int dt = 0; dt < 4; ++dt)
#pragma unroll
      for (int r = 0; r < 4; ++r) oacc[dt][r] = 0.f;

    const int t_wave_hi = q0 + 16 * w + 15;

    int cur = 0;
    stage(0, 0);

#pragma unroll 1
    for (int kvb = 0; kvb <= qi; ++kvb) {
      const int s0 = kvb * 64;
      const bool diag = (kvb == qi);

      if (kvb < qi) {
        stage(cur ^ 1, kvb + 1);                          // prefetch next tile
        asm volatile("s_waitcnt vmcnt(4)" ::: "memory");  // current tile landed
      } else {
        asm volatile("s_waitcnt vmcnt(0)" ::: "memory");
      }
      __builtin_amdgcn_s_barrier();
      __builtin_amdgcn_sched_barrier(0);

      // ---- swapped QK^T: sacc[j] = S^T, lane holds S^T[s=16j+4lq+r][t=l15] ----
      f32x4 sacc[4];
#pragma unroll
      for (int j = 0; j < 4; ++j)
#pragma unroll
        for (int r = 0; r < 4; ++r) sacc[j][r] = 0.f;
#pragma unroll
      for (int j = 0; j < 4; ++j) {
        if (!diag || s0 + 16 * j <= t_wave_hi) {   // wave-uniform skip
          const char* krow = kbase + cur * 8192 + (16 * j + l15) * 128;
          bf16x8 bk0 = *reinterpret_cast<const bf16x8*>(krow + selA);
          bf16x8 bk1 = *reinterpret_cast<const bf16x8*>(krow + selB);
          sacc[j] = __builtin_amdgcn_mfma_f32_16x16x32_bf16(bk0, bq0, sacc[j], 0, 0, 0);
          sacc[j] = __builtin_amdgcn_mfma_f32_16x16x32_bf16(bk1, bq1, sacc[j], 0, 0, 0);
        }
      }

      // ---- causal mask (diag only) ----
      float vals[4][4];
      if (diag) {
#pragma unroll
        for (int j = 0; j < 4; ++j)
#pragma unroll
          for (int r = 0; r < 4; ++r) {
            const int srow = s0 + 16 * j + 4 * lq + r;
            vals[j][r] = (srow <= tq) ? sacc[j][r] : NEGI;
          }
      } else {
#pragma unroll
        for (int j = 0; j < 4; ++j)
#pragma unroll
          for (int r = 0; r < 4; ++r) vals[j][r] = sacc[j][r];
      }

      // ---- row max: in-lane tree + 2 shfl (cross-lq, same q row) ----
      float m4[4];
#pragma unroll
      for (int j = 0; j < 4; ++j)
        m4[j] = fmaxf(fmaxf(vals[j][0], vals[j][1]), fmaxf(vals[j][2], vals[j][3]));
      float bm = fmaxf(fmaxf(m4[0], m4[1]), fmaxf(m4[2], m4[3]));
      bm = fmaxf(bm, __shfl_xor(bm, 16));
      bm = fmaxf(bm, __shfl_xor(bm, 32));

      // ---- defer-rescale (wave-uniform) ----
      if (__any(bm > m + THR)) {
        const float newm = fmaxf(m, bm);
        const float es = exp2f(m - newm);
        lsum *= es;
#pragma unroll
        for (int dt = 0; dt < 4; ++dt)
#pragma unroll
          for (int r = 0; r < 4; ++r) oacc[dt][r] *= es;
        m = newm;
      }

      // ---- P = exp2(S^T - m), row sum, pack to bf16 pairs ----
      float p[4][4];
#pragma unroll
      for (int j = 0; j < 4; ++j)
#pragma unroll
        for (int r = 0; r < 4; ++r) p[j][r] = exp2f(vals[j][r] - m);
      float s4[4];
#pragma unroll
      for (int j = 0; j < 4; ++j)
        s4[j] = (p[j][0] + p[j][1]) + (p[j][2] + p[j][3]);
      float ps = (s4[0] + s4[1]) + (s4[2] + s4[3]);
      ps += __shfl_xor(ps, 16);
      ps += __shfl_xor(ps, 32);
      lsum += ps;

      unsigned Dw[4][2];
#pragma unroll
      for (int j = 0; j < 4; ++j) {
        Dw[j][0] = pk2(p[j][0], p[j][1]);
        Dw[j][1] = pk2(p[j][2], p[j][3]);
      }

      // ---- assemble P^T B-fragments in-register (16 shfl + 8 select) ----
      bf16x8 pt[2];
#pragma unroll
      for (int c = 0; c < 2; ++c) {
        const int jl = 2 * c, jh = 2 * c + 1;
        unsigned a0 = __shfl(Dw[jl][0], srcA), a1 = __shfl(Dw[jl][1], srcA);
        unsigned a2 = __shfl(Dw[jl][0], srcB), a3 = __shfl(Dw[jl][1], srcB);
        unsigned b0 = __shfl(Dw[jh][0], srcA), b1 = __shfl(Dw[jh][1], srcA);
        unsigned b2 = __shfl(Dw[jh][0], srcB), b3 = __shfl(Dw[jh][1], srcB);
        union { unsigned u[4]; bf16x8 v; } uu;
        uu.u[0] = hiq ? b0 : a0;
        uu.u[1] = hiq ? b1 : a1;
        uu.u[2] = hiq ? b2 : a2;
        uu.u[3] = hiq ? b3 : a3;
        pt[c] = uu.v;
      }

      // ---- PV (O^T): oacc[dt] holds O[t=l15][d=16dt+4lq+r] ----
#pragma unroll
      for (int dt = 0; dt < 4; ++dt) {
        const char* vrow = vbase + cur * 8192 + (16 * dt + l15) * 128;
        bf16x8 bv0 = *reinterpret_cast<const bf16x8*>(vrow + selA);
        bf16x8 bv1 = *reinterpret_cast<const bf16x8*>(vrow + selB);
        oacc[dt] = __builtin_amdgcn_mfma_f32_16x16x32_bf16(bv0, pt[0], oacc[dt], 0, 0, 0);
        oacc[dt] = __builtin_amdgcn_mfma_f32_16x16x32_bf16(bv1, pt[1], oacc[dt], 0, 0, 0);
      }

      __builtin_amdgcn_s_barrier();   // all reads of buf[cur] done before reuse
      cur ^= 1;
    }

    // ---- epilogue: normalize, float4 stores (lane owns row tq, d = 16dt+4lq+r) ----
    const float inv = 1.f / lsum;
    float* orow = out + (((size_t)(b * Ssz + tq) * Hsz) + h) * Dsz;
#pragma unroll
    for (int dt = 0; dt < 4; ++dt) {
      float4 st;
      st.x = oacc[dt][0] * inv;
      st.y = oacc[dt][1] * inv;
      st.z = oacc[dt][2] * inv;
      st.w = oacc[dt][3] * inv;
      *reinterpret_cast<float4*>(orow + 16 * dt + 4 * lq) = st;
    }
  }
}

// ---------------- fallback (round-2 kernel) if ws too small ----------------
constexpr int QT = 64;
constexpr int KT = 64;
constexpr int LDKfb = 72;

__global__ __launch_bounds__(256)
void attn_fwd_fb(const float* __restrict__ qkv, float* __restrict__ out) {
  const int qi   = (Ssz / QT) - 1 - (int)blockIdx.x;
  const int bh   = blockIdx.y;
  const int b    = bh >> 4;
  const int h    = bh & 15;
  const int tid  = threadIdx.x;
  const int wave = tid >> 6;
  const int lane = tid & 63;
  const int l15  = lane & 15;
  const int lq   = lane >> 4;
  const int q0   = qi * QT;

  __shared__ short Kl[KT][LDKfb];
  __shared__ short Vtl[Dsz][LDKfb];
  __shared__ short Pl[4][16][LDKfb];

  bf16x8 aq[2];
  {
    const int tqf = q0 + wave * 16 + l15;
    const float* qrowf = qkv + (((size_t)(b * Ssz + tqf) * 3 + 0) * Hsz + h) * Dsz;
#pragma unroll
    for (int c = 0; c < 2; ++c) {
      const float* p = qrowf + 32 * c + 8 * lq;
      float4 f0 = reinterpret_cast<const float4*>(p)[0];
      float4 f1 = reinterpret_cast<const float4*>(p)[1];
      bf16x8 v;
      v[0] = f2b(f0.x); v[1] = f2b(f0.y); v[2] = f2b(f0.z); v[3] = f2b(f0.w);
      v[4] = f2b(f1.x); v[5] = f2b(f1.y); v[6] = f2b(f1.z); v[7] = f2b(f1.w);
      aq[c] = v;
    }
  }

  float mrow[4], lsum[4];
  f32x4 oacc[4];
#pragma unroll
  for (int r = 0; r < 4; ++r) { mrow[r] = NEGI; lsum[r] = 0.f; }
#pragma unroll
  for (int dt = 0; dt < 4; ++dt)
#pragma unroll
    for (int r = 0; r < 4; ++r) oacc[dt][r] = 0.f;

  const int t_wave_hi = q0 + wave * 16 + 15;
  const int trow      = q0 + wave * 16 + 4 * lq;
  const int nkv       = qi + 1;

  const int pr   = tid >> 3;
  const int srow = 2 * pr;
  const int d0   = (tid & 7) * 8;
  const int Fw   = tid & 7;
  const int swc  = srow ^ (Fw << 3);

  for (int kvb = 0; kvb < nkv; ++kvb) {
    const int s0 = kvb * KT;
    {
      const float* kr0 = qkv + (((size_t)(b * Ssz + s0 + srow) * 3 + 1) * Hsz + h) * Dsz + d0;
      const float* kr1 = kr0 + 3 * Hsz * Dsz;
      const float* vr0 = kr0 + Hsz * Dsz;
      const float* vr1 = vr0 + 3 * Hsz * Dsz;
      float4 ka0 = reinterpret_cast<const float4*>(kr0)[0];
      float4 ka1 = reinterpret_cast<const float4*>(kr0)[1];
      float4 kb0 = reinterpret_cast<const float4*>(kr1)[0];
      float4 kb1 = reinterpret_cast<const float4*>(kr1)[1];
      float4 va0 = reinterpret_cast<const float4*>(vr0)[0];
      float4 va1 = reinterpret_cast<const float4*>(vr0)[1];
      float4 vb0 = reinterpret_cast<const float4*>(vr1)[0];
      float4 vb1 = reinterpret_cast<const float4*>(vr1)[1];

      bf16x8 kw0, kw1;
      kw0[0] = f2b(ka0.x); kw0[1] = f2b(ka0.y); kw0[2] = f2b(ka0.z); kw0[3] = f2b(ka0.w);
      kw0[4] = f2b(ka1.x); kw0[5] = f2b(ka1.y); kw0[6] = f2b(ka1.z); kw0[7] = f2b(ka1.w);
      kw1[0] = f2b(kb0.x); kw1[1] = f2b(kb0.y); kw1[2] = f2b(kb0.z); kw1[3] = f2b(kb0.w);
      kw1[4] = f2b(kb1.x); kw1[5] = f2b(kb1.y); kw1[6] = f2b(kb1.z); kw1[7] = f2b(kb1.w);
      *reinterpret_cast<bf16x8*>(&Kl[srow][d0])     = kw0;
      *reinterpret_cast<bf16x8*>(&Kl[srow + 1][d0]) = kw1;

      float va[8] = {va0.x, va0.y, va0.z, va0.w, va1.x, va1.y, va1.z, va1.w};
      float vb[8] = {vb0.x, vb0.y, vb0.z, vb0.w, vb1.x, vb1.y, vb1.z, vb1.w};
#pragma unroll
      for (int j = 0; j < 8; ++j) {
        __hip_bfloat162 h2 = __float22bfloat162_rn(make_float2(va[j], vb[j]));
        *reinterpret_cast<unsigned*>(&Vtl[d0 + j][swc]) =
            *reinterpret_cast<unsigned*>(&h2);
      }
    }
    __syncthreads();

    f32x4 sacc[4];
#pragma unroll
    for (int j = 0; j < 4; ++j)
#pragma unroll
      for (int r = 0; r < 4; ++r) sacc[j][r] = 0.f;
#pragma unroll
    for (int j = 0; j < 4; ++j) {
      if (s0 + 16 * j <= t_wave_hi) {
#pragma unroll
        for (int c = 0; c < 2; ++c) {
          bf16x8 bk = *reinterpret_cast<const bf16x8*>(&Kl[16 * j + l15][32 * c + 8 * lq]);
          sacc[j] = __builtin_amdgcn_mfma_f32_16x16x32_bf16(aq[c], bk, sacc[j], 0, 0, 0);
        }
      }
    }

    const bool diag = (kvb == nkv - 1);
    float vals[4][4], bm[4];
#pragma unroll
    for (int r = 0; r < 4; ++r) bm[r] = NEGI;
    if (diag) {
#pragma unroll
      for (int j = 0; j < 4; ++j) {
        const bool actj = (s0 + 16 * j <= t_wave_hi);
        const int scol = s0 + 16 * j + l15;
#pragma unroll
        for (int r = 0; r < 4; ++r) {
          float v = (actj && scol <= trow + r) ? sacc[j][r] * SCL2 : NEGI;
          vals[j][r] = v;
          bm[r] = fmaxf(bm[r], v);
        }
      }
    } else {
#pragma unroll
      for (int j = 0; j < 4; ++j)
#pragma unroll
        for (int r = 0; r < 4; ++r) {
          float v = sacc[j][r] * SCL2;
          vals[j][r] = v;
          bm[r] = fmaxf(bm[r], v);
        }
    }
#pragma unroll
    for (int off = 1; off < 16; off <<= 1)
#pragma unroll
      for (int r = 0; r < 4; ++r)
        bm[r] = fmaxf(bm[r], __shfl_xor(bm[r], off));

    float es[4], ps[4];
#pragma unroll
    for (int r = 0; r < 4; ++r) {
      const float mn = fmaxf(mrow[r], bm[r]);
      es[r] = exp2f(mrow[r] - mn);
      mrow[r] = mn;
      ps[r] = 0.f;
    }
#pragma unroll
    for (int j = 0; j < 4; ++j)
#pragma unroll
      for (int r = 0; r < 4; ++r) {
        float p = exp2f(vals[j][r] - mrow[r]);
        ps[r] += p;
        Pl[wave][4 * lq + r][16 * j + l15] = f2b(p);
      }
#pragma unroll
    for (int off = 1; off < 16; off <<= 1)
#pragma unroll
      for (int r = 0; r < 4; ++r)
        ps[r] += __shfl_xor(ps[r], off);
#pragma unroll
    for (int r = 0; r < 4; ++r)
      lsum[r] = lsum[r] * es[r] + ps[r];
#pragma unroll
    for (int dt = 0; dt < 4; ++dt)
#pragma unroll
      for (int r = 0; r < 4; ++r)
        oacc[dt][r] *= es[r];

    asm volatile("" ::: "memory");

    {
      bf16x8 ap0 = *reinterpret_cast<const bf16x8*>(&Pl[wave][l15][8 * lq]);
      bf16x8 ap1 = *reinterpret_cast<const bf16x8*>(&Pl[wave][l15][32 + 8 * lq]);
#pragma unroll
      for (int dt = 0; dt < 4; ++dt) {
        const int d = 16 * dt + l15;
        const int F = (d >> 3) & 7;
        bf16x8 bv0 = *reinterpret_cast<const bf16x8*>(&Vtl[d][((lq ^ F) << 3)]);
        bf16x8 bv1 = *reinterpret_cast<const bf16x8*>(&Vtl[d][(((4 + lq) ^ F) << 3)]);
        oacc[dt] = __builtin_amdgcn_mfma_f32_16x16x32_bf16(ap0, bv0, oacc[dt], 0, 0, 0);
        oacc[dt] = __builtin_amdgcn_mfma_f32_16x16x32_bf16(ap1, bv1, oacc[dt], 0, 0, 0);
      }
    }
    __syncthreads();
  }

#pragma unroll
  for (int r = 0; r < 4; ++r) {
    const float inv = 1.f / lsum[r];
    const int t = trow + r;
    float* orow = out + (((size_t)(b * Ssz + t) * Hsz) + h) * Dsz;
#pragma unroll
    for (int dt = 0; dt < 4; ++dt)
      orow[16 * dt + l15] = oacc[dt][r] * inv;
  }
}

extern "C" void kernel_launch(void* const* d_in, const int* in_sizes, int n_in,
                              void* d_out, int out_size, void* d_ws, size_t ws_size,
                              hipStream_t stream) {
  const float* qkv = (const float*)d_in[0];
  float* out = (float*)d_out;
  const size_t need = 3 * NEL * sizeof(short);  // 25,165,824 B
  if (ws_size >= need) {
    short* Qb = (short*)d_ws;
    short* Kt = Qb + NEL;
    short* Vt = Qb + 2 * NEL;
    hipLaunchKernelGGL(prep_qk, dim3((unsigned)(NEL / 8 / 256), 2), dim3(256), 0, stream, qkv, Qb);
    hipLaunchKernelGGL(prep_vt, dim3(Ssz / 64, BH), dim3(256), 0, stream, qkv, Vt);
    hipLaunchKernelGGL(attn_main, dim3(16, BH), dim3(256), 0, stream, Qb, Kt, Vt, out);
  } else {
    hipLaunchKernelGGL(attn_fwd_fb, dim3(Ssz / QT, BH), dim3(256), 0, stream, qkv, out);
  }
}

// Round 9
// 87.993 us; speedup vs baseline: 2.5279x; 1.0229x over previous
//
#include <hip/hip_runtime.h>
#include <hip/hip_bf16.h>

// Causal self-attention fwd, B=2 S=2048 H=16 D=64, f32 in/out, bf16 MFMA inside.
// Round 9: round-8 body unchanged; staging latency attacked two ways:
//  (1) grid (bh, pair) so the 16 same-bh blocks co-locate on one XCD -> K/V
//      workspace is L2-resident (2 MB/XCD working set).
//  (2) quad-buffered global_load_lds staging, prefetch depth 3, counted
//      vmcnt(12) steady-state (drain 8/4/0 at tail).

#define Bsz 2
#define Ssz 2048
#define Hsz 16
#define Dsz 64
#define BH (Bsz * Hsz)

typedef short bf16x8 __attribute__((ext_vector_type(8)));
typedef float f32x4  __attribute__((ext_vector_type(4)));

constexpr float SCL2 = 0.125f * 1.44269504088896340736f;  // scale * log2(e)
constexpr float NEGI = -1e30f;
constexpr float THR  = 10.0f;   // defer-rescale threshold (exp2 domain)
constexpr size_t NEL = (size_t)BH * Ssz * Dsz;  // 4,194,304 shorts per array

__device__ __forceinline__ short f2b(float f) {
  __hip_bfloat16 h = __float2bfloat16(f);
  return *reinterpret_cast<short*>(&h);
}

__device__ __forceinline__ unsigned pk2(float a, float b) {
  __hip_bfloat162 h2 = __float22bfloat162_rn(make_float2(a, b));
  unsigned u; __builtin_memcpy(&u, &h2, 4); return u;
}

typedef const __attribute__((address_space(1))) unsigned int* gas_p;
typedef __attribute__((address_space(3))) unsigned int* las_p;

__device__ __forceinline__ void lds16(const short* g, short* l) {
  gas_p gp = (gas_p)(uintptr_t)g;
  las_p lp = (las_p)(uintptr_t)l;
  __builtin_amdgcn_global_load_lds(gp, lp, 16, 0, 0);
}

// ---------------- pre-pass: Q (pre-scaled) and K (pre-swizzled tiles) ----------------
__global__ __launch_bounds__(256)
void prep_qk(const float* __restrict__ qkv, short* __restrict__ dst0) {
  const int which = blockIdx.y;  // 0 = Q, 1 = K
  const int T = blockIdx.x * 256 + threadIdx.x;
  const int p  = T & 7;
  const int s  = (T >> 3) & (Ssz - 1);
  const int bh = T >> 14;
  const int b = bh >> 4, h = bh & 15;
  const int c = which ? (p ^ (s & 7)) : p;   // source 8-elem chunk within row
  const float sc = which ? 1.0f : SCL2;      // fold softmax scale into Q
  const float* src = qkv + (((size_t)(b * Ssz + s) * 3 + which) * Hsz + h) * Dsz + 8 * c;
  float4 f0 = reinterpret_cast<const float4*>(src)[0];
  float4 f1 = reinterpret_cast<const float4*>(src)[1];
  bf16x8 v;
  v[0] = f2b(f0.x * sc); v[1] = f2b(f0.y * sc); v[2] = f2b(f0.z * sc); v[3] = f2b(f0.w * sc);
  v[4] = f2b(f1.x * sc); v[5] = f2b(f1.y * sc); v[6] = f2b(f1.z * sc); v[7] = f2b(f1.w * sc);
  *reinterpret_cast<bf16x8*>(dst0 + (size_t)which * NEL + (size_t)T * 8) = v;
}

// ---------------- pre-pass: V -> V^T pre-swizzled tiles ----------------
__global__ __launch_bounds__(256)
void prep_vt(const float* __restrict__ qkv, short* __restrict__ vt) {
  __shared__ short Ls[64][72];
  const int tile = blockIdx.x;
  const int s0 = tile * 64;
  const int bh = blockIdx.y;
  const int b = bh >> 4, h = bh & 15;
  const int t = threadIdx.x;
  {
    const int srow = t >> 2;
    const int dc = (t & 3) * 16;
    const float* src = qkv + (((size_t)(b * Ssz + s0 + srow) * 3 + 2) * Hsz + h) * Dsz + dc;
    float4 a0 = reinterpret_cast<const float4*>(src)[0];
    float4 a1 = reinterpret_cast<const float4*>(src)[1];
    float4 a2 = reinterpret_cast<const float4*>(src)[2];
    float4 a3 = reinterpret_cast<const float4*>(src)[3];
    bf16x8 lo, hi;
    lo[0] = f2b(a0.x); lo[1] = f2b(a0.y); lo[2] = f2b(a0.z); lo[3] = f2b(a0.w);
    lo[4] = f2b(a1.x); lo[5] = f2b(a1.y); lo[6] = f2b(a1.z); lo[7] = f2b(a1.w);
    hi[0] = f2b(a2.x); hi[1] = f2b(a2.y); hi[2] = f2b(a2.z); hi[3] = f2b(a2.w);
    hi[4] = f2b(a3.x); hi[5] = f2b(a3.y); hi[6] = f2b(a3.z); hi[7] = f2b(a3.w);
    *reinterpret_cast<bf16x8*>(&Ls[srow][dc])     = lo;
    *reinterpret_cast<bf16x8*>(&Ls[srow][dc + 8]) = hi;
  }
  __syncthreads();
  {
    const int d = t >> 2;
    short* drow = vt + (size_t)bh * (32 * 4096) + (size_t)tile * 4096 + d * 64;
#pragma unroll
    for (int pp = 0; pp < 2; ++pp) {
      const int p = (t & 3) * 2 + pp;
      const int sbase = 8 * (p ^ (d & 7));
      bf16x8 w;
#pragma unroll
      for (int e = 0; e < 8; ++e) w[e] = Ls[sbase + e][d];
      *reinterpret_cast<bf16x8*>(drow + p * 8) = w;
    }
  }
}

// ---------------- main: flash attention, paired q-tiles, quad-buffer staging ----------------
__global__ __launch_bounds__(256)
void attn_main(const short* __restrict__ Qb, const short* __restrict__ Kt,
               const short* __restrict__ Vt, float* __restrict__ out) {
  const int bh   = blockIdx.x;          // linear id = bh + 32*pair -> XCD = bh%8
  const int pair = blockIdx.y;          // 0..15 -> tiles (pair, 31-pair)
  const int b = bh >> 4, h = bh & 15;
  const int tid = threadIdx.x;
  const int w = tid >> 6, lane = tid & 63, l15 = lane & 15, lq = lane >> 4;

  __shared__ short Kbuf[4][4096];   // 4 x 8KB, swizzled [64 s][8 chunk]
  __shared__ short Vbuf[4][4096];   // 4 x 8KB, swizzled [64 d][8 chunk]

  const short* Ksrc = Kt + (size_t)bh * (32 * 4096);
  const short* Vsrc = Vt + (size_t)bh * (32 * 4096);

  // tile-invariant swizzled ds_read offsets: row*128 + ((chunk ^ (l15&7))<<4)
  const int selA = ((lq)     ^ (l15 & 7)) << 4;
  const int selB = ((4 + lq) ^ (l15 & 7)) << 4;
  const char* kbase = (const char*)Kbuf;
  const char* vbase = (const char*)Vbuf;

  // bpermute source lanes for P^T exchange
  const int srcA = ((2 * lq) & 3) * 16 + l15;
  const int srcB = ((2 * lq + 1) & 3) * 16 + l15;
  const bool hiq = (lq >= 2);

  auto stage = [&](int kvb) {
    const int buf = kvb & 3;
    const short* ks = Ksrc + (size_t)kvb * 4096;
    const short* vs = Vsrc + (size_t)kvb * 4096;
    short* kl = (short*)((char*)Kbuf + buf * 8192 + w * 1024);
    short* vl = (short*)((char*)Vbuf + buf * 8192 + w * 1024);
    lds16(ks + (w * 64 + lane) * 8, kl);
    lds16(ks + (256 + w * 64 + lane) * 8, (short*)((char*)kl + 4096));
    lds16(vs + (w * 64 + lane) * 8, vl);
    lds16(vs + (256 + w * 64 + lane) * 8, (short*)((char*)vl + 4096));
  };

#pragma unroll 1
  for (int half = 0; half < 2; ++half) {
    const int qi = half ? (31 - pair) : pair;
    const int q0 = qi * 64;

    // Q fragment (B operand of swapped QK^T): col = l15 (q row), k(d) = 32c + 8lq + e
    const int tq = q0 + 16 * w + l15;
    const short* qrow = Qb + ((size_t)bh * Ssz + tq) * Dsz;
    const bf16x8 bq0 = *reinterpret_cast<const bf16x8*>(qrow + 8 * lq);
    const bf16x8 bq1 = *reinterpret_cast<const bf16x8*>(qrow + 32 + 8 * lq);

    float m = NEGI, lsum = 0.f;
    f32x4 oacc[4];
#pragma unroll
    for (int dt = 0; dt < 4; ++dt)
#pragma unroll
      for (int r = 0; r < 4; ++r) oacc[dt][r] = 0.f;

    const int t_wave_hi = q0 + 16 * w + 15;

    // prologue: prefetch up to 3 tiles
    stage(0);
    if (qi >= 1) stage(1);
    if (qi >= 2) stage(2);

#pragma unroll 1
    for (int kvb = 0; kvb <= qi; ++kvb) {
      const int s0 = kvb * 64;
      const bool diag = (kvb == qi);
      const int cur = kvb & 3;

      if (kvb + 3 <= qi) {
        stage(kvb + 3);                                    // prefetch 3 ahead
        asm volatile("s_waitcnt vmcnt(12)" ::: "memory");  // tile kvb landed
      } else {
        const int rem = qi - kvb;  // 2, 1, 0 at tail
        if (rem == 2)      asm volatile("s_waitcnt vmcnt(8)" ::: "memory");
        else if (rem == 1) asm volatile("s_waitcnt vmcnt(4)" ::: "memory");
        else               asm volatile("s_waitcnt vmcnt(0)" ::: "memory");
      }
      __builtin_amdgcn_s_barrier();
      __builtin_amdgcn_sched_barrier(0);

      // ---- swapped QK^T: sacc[j] = S^T, lane holds S^T[s=16j+4lq+r][t=l15] ----
      f32x4 sacc[4];
#pragma unroll
      for (int j = 0; j < 4; ++j)
#pragma unroll
        for (int r = 0; r < 4; ++r) sacc[j][r] = 0.f;
#pragma unroll
      for (int j = 0; j < 4; ++j) {
        if (!diag || s0 + 16 * j <= t_wave_hi) {   // wave-uniform skip
          const char* krow = kbase + cur * 8192 + (16 * j + l15) * 128;
          bf16x8 bk0 = *reinterpret_cast<const bf16x8*>(krow + selA);
          bf16x8 bk1 = *reinterpret_cast<const bf16x8*>(krow + selB);
          sacc[j] = __builtin_amdgcn_mfma_f32_16x16x32_bf16(bk0, bq0, sacc[j], 0, 0, 0);
          sacc[j] = __builtin_amdgcn_mfma_f32_16x16x32_bf16(bk1, bq1, sacc[j], 0, 0, 0);
        }
      }

      // ---- causal mask (diag only) ----
      float vals[4][4];
      if (diag) {
#pragma unroll
        for (int j = 0; j < 4; ++j)
#pragma unroll
          for (int r = 0; r < 4; ++r) {
            const int srow = s0 + 16 * j + 4 * lq + r;
            vals[j][r] = (srow <= tq) ? sacc[j][r] : NEGI;
          }
      } else {
#pragma unroll
        for (int j = 0; j < 4; ++j)
#pragma unroll
          for (int r = 0; r < 4; ++r) vals[j][r] = sacc[j][r];
      }

      // ---- row max: in-lane tree + 2 shfl (cross-lq, same q row) ----
      float m4[4];
#pragma unroll
      for (int j = 0; j < 4; ++j)
        m4[j] = fmaxf(fmaxf(vals[j][0], vals[j][1]), fmaxf(vals[j][2], vals[j][3]));
      float bm = fmaxf(fmaxf(m4[0], m4[1]), fmaxf(m4[2], m4[3]));
      bm = fmaxf(bm, __shfl_xor(bm, 16));
      bm = fmaxf(bm, __shfl_xor(bm, 32));

      // ---- defer-rescale (wave-uniform) ----
      if (__any(bm > m + THR)) {
        const float newm = fmaxf(m, bm);
        const float es = exp2f(m - newm);
        lsum *= es;
#pragma unroll
        for (int dt = 0; dt < 4; ++dt)
#pragma unroll
          for (int r = 0; r < 4; ++r) oacc[dt][r] *= es;
        m = newm;
      }

      // ---- P = exp2(S^T - m), row sum, pack to bf16 pairs ----
      float p[4][4];
#pragma unroll
      for (int j = 0; j < 4; ++j)
#pragma unroll
        for (int r = 0; r < 4; ++r) p[j][r] = exp2f(vals[j][r] - m);
      float s4[4];
#pragma unroll
      for (int j = 0; j < 4; ++j)
        s4[j] = (p[j][0] + p[j][1]) + (p[j][2] + p[j][3]);
      float ps = (s4[0] + s4[1]) + (s4[2] + s4[3]);
      ps += __shfl_xor(ps, 16);
      ps += __shfl_xor(ps, 32);
      lsum += ps;

      unsigned Dw[4][2];
#pragma unroll
      for (int j = 0; j < 4; ++j) {
        Dw[j][0] = pk2(p[j][0], p[j][1]);
        Dw[j][1] = pk2(p[j][2], p[j][3]);
      }

      // ---- assemble P^T B-fragments in-register (16 shfl + 8 select) ----
      bf16x8 pt[2];
#pragma unroll
      for (int c = 0; c < 2; ++c) {
        const int jl = 2 * c, jh = 2 * c + 1;
        unsigned a0 = __shfl(Dw[jl][0], srcA), a1 = __shfl(Dw[jl][1], srcA);
        unsigned a2 = __shfl(Dw[jl][0], srcB), a3 = __shfl(Dw[jl][1], srcB);
        unsigned b0 = __shfl(Dw[jh][0], srcA), b1 = __shfl(Dw[jh][1], srcA);
        unsigned b2 = __shfl(Dw[jh][0], srcB), b3 = __shfl(Dw[jh][1], srcB);
        union { unsigned u[4]; bf16x8 v; } uu;
        uu.u[0] = hiq ? b0 : a0;
        uu.u[1] = hiq ? b1 : a1;
        uu.u[2] = hiq ? b2 : a2;
        uu.u[3] = hiq ? b3 : a3;
        pt[c] = uu.v;
      }

      // ---- PV (O^T): oacc[dt] holds O[t=l15][d=16dt+4lq+r] ----
#pragma unroll
      for (int dt = 0; dt < 4; ++dt) {
        const char* vrow = vbase + cur * 8192 + (16 * dt + l15) * 128;
        bf16x8 bv0 = *reinterpret_cast<const bf16x8*>(vrow + selA);
        bf16x8 bv1 = *reinterpret_cast<const bf16x8*>(vrow + selB);
        oacc[dt] = __builtin_amdgcn_mfma_f32_16x16x32_bf16(bv0, pt[0], oacc[dt], 0, 0, 0);
        oacc[dt] = __builtin_amdgcn_mfma_f32_16x16x32_bf16(bv1, pt[1], oacc[dt], 0, 0, 0);
      }

      __builtin_amdgcn_s_barrier();   // all reads of buf[cur] done before reuse
    }

    // ---- epilogue: normalize, float4 stores (lane owns row tq, d = 16dt+4lq+r) ----
    const float inv = 1.f / lsum;
    float* orow = out + (((size_t)(b * Ssz + tq) * Hsz) + h) * Dsz;
#pragma unroll
    for (int dt = 0; dt < 4; ++dt) {
      float4 st;
      st.x = oacc[dt][0] * inv;
      st.y = oacc[dt][1] * inv;
      st.z = oacc[dt][2] * inv;
      st.w = oacc[dt][3] * inv;
      *reinterpret_cast<float4*>(orow + 16 * dt + 4 * lq) = st;
    }
  }
}

// ---------------- fallback (round-2 kernel) if ws too small ----------------
constexpr int QT = 64;
constexpr int KT = 64;
constexpr int LDKfb = 72;

__global__ __launch_bounds__(256)
void attn_fwd_fb(const float* __restrict__ qkv, float* __restrict__ out) {
  const int qi   = (Ssz / QT) - 1 - (int)blockIdx.x;
  const int bh   = blockIdx.y;
  const int b    = bh >> 4;
  const int h    = bh & 15;
  const int tid  = threadIdx.x;
  const int wave = tid >> 6;
  const int lane = tid & 63;
  const int l15  = lane & 15;
  const int lq   = lane >> 4;
  const int q0   = qi * QT;

  __shared__ short Kl[KT][LDKfb];
  __shared__ short Vtl[Dsz][LDKfb];
  __shared__ short Pl[4][16][LDKfb];

  bf16x8 aq[2];
  {
    const int tqf = q0 + wave * 16 + l15;
    const float* qrowf = qkv + (((size_t)(b * Ssz + tqf) * 3 + 0) * Hsz + h) * Dsz;
#pragma unroll
    for (int c = 0; c < 2; ++c) {
      const float* p = qrowf + 32 * c + 8 * lq;
      float4 f0 = reinterpret_cast<const float4*>(p)[0];
      float4 f1 = reinterpret_cast<const float4*>(p)[1];
      bf16x8 v;
      v[0] = f2b(f0.x); v[1] = f2b(f0.y); v[2] = f2b(f0.z); v[3] = f2b(f0.w);
      v[4] = f2b(f1.x); v[5] = f2b(f1.y); v[6] = f2b(f1.z); v[7] = f2b(f1.w);
      aq[c] = v;
    }
  }

  float mrow[4], lsum[4];
  f32x4 oacc[4];
#pragma unroll
  for (int r = 0; r < 4; ++r) { mrow[r] = NEGI; lsum[r] = 0.f; }
#pragma unroll
  for (int dt = 0; dt < 4; ++dt)
#pragma unroll
    for (int r = 0; r < 4; ++r) oacc[dt][r] = 0.f;

  const int t_wave_hi = q0 + wave * 16 + 15;
  const int trow      = q0 + wave * 16 + 4 * lq;
  const int nkv       = qi + 1;

  const int pr   = tid >> 3;
  const int srow = 2 * pr;
  const int d0   = (tid & 7) * 8;
  const int Fw   = tid & 7;
  const int swc  = srow ^ (Fw << 3);

  for (int kvb = 0; kvb < nkv; ++kvb) {
    const int s0 = kvb * KT;
    {
      const float* kr0 = qkv + (((size_t)(b * Ssz + s0 + srow) * 3 + 1) * Hsz + h) * Dsz + d0;
      const float* kr1 = kr0 + 3 * Hsz * Dsz;
      const float* vr0 = kr0 + Hsz * Dsz;
      const float* vr1 = vr0 + 3 * Hsz * Dsz;
      float4 ka0 = reinterpret_cast<const float4*>(kr0)[0];
      float4 ka1 = reinterpret_cast<const float4*>(kr0)[1];
      float4 kb0 = reinterpret_cast<const float4*>(kr1)[0];
      float4 kb1 = reinterpret_cast<const float4*>(kr1)[1];
      float4 va0 = reinterpret_cast<const float4*>(vr0)[0];
      float4 va1 = reinterpret_cast<const float4*>(vr0)[1];
      float4 vb0 = reinterpret_cast<const float4*>(vr1)[0];
      float4 vb1 = reinterpret_cast<const float4*>(vr1)[1];

      bf16x8 kw0, kw1;
      kw0[0] = f2b(ka0.x); kw0[1] = f2b(ka0.y); kw0[2] = f2b(ka0.z); kw0[3] = f2b(ka0.w);
      kw0[4] = f2b(ka1.x); kw0[5] = f2b(ka1.y); kw0[6] = f2b(ka1.z); kw0[7] = f2b(ka1.w);
      kw1[0] = f2b(kb0.x); kw1[1] = f2b(kb0.y); kw1[2] = f2b(kb0.z); kw1[3] = f2b(kb0.w);
      kw1[4] = f2b(kb1.x); kw1[5] = f2b(kb1.y); kw1[6] = f2b(kb1.z); kw1[7] = f2b(kb1.w);
      *reinterpret_cast<bf16x8*>(&Kl[srow][d0])     = kw0;
      *reinterpret_cast<bf16x8*>(&Kl[srow + 1][d0]) = kw1;

      float va[8] = {va0.x, va0.y, va0.z, va0.w, va1.x, va1.y, va1.z, va1.w};
      float vb[8] = {vb0.x, vb0.y, vb0.z, vb0.w, vb1.x, vb1.y, vb1.z, vb1.w};
#pragma unroll
      for (int j = 0; j < 8; ++j) {
        __hip_bfloat162 h2 = __float22bfloat162_rn(make_float2(va[j], vb[j]));
        *reinterpret_cast<unsigned*>(&Vtl[d0 + j][swc]) =
            *reinterpret_cast<unsigned*>(&h2);
      }
    }
    __syncthreads();

    f32x4 sacc[4];
#pragma unroll
    for (int j = 0; j < 4; ++j)
#pragma unroll
      for (int r = 0; r < 4; ++r) sacc[j][r] = 0.f;
#pragma unroll
    for (int j = 0; j < 4; ++j) {
      if (s0 + 16 * j <= t_wave_hi) {
#pragma unroll
        for (int c = 0; c < 2; ++c) {
          bf16x8 bk = *reinterpret_cast<const bf16x8*>(&Kl[16 * j + l15][32 * c + 8 * lq]);
          sacc[j] = __builtin_amdgcn_mfma_f32_16x16x32_bf16(aq[c], bk, sacc[j], 0, 0, 0);
        }
      }
    }

    const bool diag = (kvb == nkv - 1);
    float vals[4][4], bm[4];
#pragma unroll
    for (int r = 0; r < 4; ++r) bm[r] = NEGI;
    if (diag) {
#pragma unroll
      for (int j = 0; j < 4; ++j) {
        const bool actj = (s0 + 16 * j <= t_wave_hi);
        const int scol = s0 + 16 * j + l15;
#pragma unroll
        for (int r = 0; r < 4; ++r) {
          float v = (actj && scol <= trow + r) ? sacc[j][r] * SCL2 : NEGI;
          vals[j][r] = v;
          bm[r] = fmaxf(bm[r], v);
        }
      }
    } else {
#pragma unroll
      for (int j = 0; j < 4; ++j)
#pragma unroll
        for (int r = 0; r < 4; ++r) {
          float v = sacc[j][r] * SCL2;
          vals[j][r] = v;
          bm[r] = fmaxf(bm[r], v);
        }
    }
#pragma unroll
    for (int off = 1; off < 16; off <<= 1)
#pragma unroll
      for (int r = 0; r < 4; ++r)
        bm[r] = fmaxf(bm[r], __shfl_xor(bm[r], off));

    float es[4], ps[4];
#pragma unroll
    for (int r = 0; r < 4; ++r) {
      const float mn = fmaxf(mrow[r], bm[r]);
      es[r] = exp2f(mrow[r] - mn);
      mrow[r] = mn;
      ps[r] = 0.f;
    }
#pragma unroll
    for (int j = 0; j < 4; ++j)
#pragma unroll
      for (int r = 0; r < 4; ++r) {
        float p = exp2f(vals[j][r] - mrow[r]);
        ps[r] += p;
        Pl[wave][4 * lq + r][16 * j + l15] = f2b(p);
      }
#pragma unroll
    for (int off = 1; off < 16; off <<= 1)
#pragma unroll
      for (int r = 0; r < 4; ++r)
        ps[r] += __shfl_xor(ps[r], off);
#pragma unroll
    for (int r = 0; r < 4; ++r)
      lsum[r] = lsum[r] * es[r] + ps[r];
#pragma unroll
    for (int dt = 0; dt < 4; ++dt)
#pragma unroll
      for (int r = 0; r < 4; ++r)
        oacc[dt][r] *= es[r];

    asm volatile("" ::: "memory");

    {
      bf16x8 ap0 = *reinterpret_cast<const bf16x8*>(&Pl[wave][l15][8 * lq]);
      bf16x8 ap1 = *reinterpret_cast<const bf16x8*>(&Pl[wave][l15][32 + 8 * lq]);
#pragma unroll
      for (int dt = 0; dt < 4; ++dt) {
        const int d = 16 * dt + l15;
        const int F = (d >> 3) & 7;
        bf16x8 bv0 = *reinterpret_cast<const bf16x8*>(&Vtl[d][((lq ^ F) << 3)]);
        bf16x8 bv1 = *reinterpret_cast<const bf16x8*>(&Vtl[d][(((4 + lq) ^ F) << 3)]);
        oacc[dt] = __builtin_amdgcn_mfma_f32_16x16x32_bf16(ap0, bv0, oacc[dt], 0, 0, 0);
        oacc[dt] = __builtin_amdgcn_mfma_f32_16x16x32_bf16(ap1, bv1, oacc[dt], 0, 0, 0);
      }
    }
    __syncthreads();
  }

#pragma unroll
  for (int r = 0; r < 4; ++r) {
    const float inv = 1.f / lsum[r];
    const int t = trow + r;
    float* orow = out + (((size_t)(b * Ssz + t) * Hsz) + h) * Dsz;
#pragma unroll
    for (int dt = 0; dt < 4; ++dt)
      orow[16 * dt + l15] = oacc[dt][r] * inv;
  }
}

extern "C" void kernel_launch(void* const* d_in, const int* in_sizes, int n_in,
                              void* d_out, int out_size, void* d_ws, size_t ws_size,
                              hipStream_t stream) {
  const float* qkv = (const float*)d_in[0];
  float* out = (float*)d_out;
  const size_t need = 3 * NEL * sizeof(short);  // 25,165,824 B
  if (ws_size >= need) {
    short* Qb = (short*)d_ws;
    short* Kt = Qb + NEL;
    short* Vt = Qb + 2 * NEL;
    hipLaunchKernelGGL(prep_qk, dim3((unsigned)(NEL / 8 / 256), 2), dim3(256), 0, stream, qkv, Qb);
    hipLaunchKernelGGL(prep_vt, dim3(Ssz / 64, BH), dim3(256), 0, stream, qkv, Vt);
    hipLaunchKernelGGL(attn_main, dim3(BH, 16), dim3(256), 0, stream, Qb, Kt, Vt, out);
  } else {
    hipLaunchKernelGGL(attn_fwd_fb, dim3(Ssz / QT, BH), dim3(256), 0, stream, qkv, out);
  }
}